// Round 1
// 167.328 us; speedup vs baseline: 1.0619x; 1.0619x over previous
//
#include <hip/hip_runtime.h>

// MRConv: B=4, C=192, N=10000, K=16, OUT=384
// out[b,o,n] = relu( sum_ch W[o,ch]*feat[b,ch,n] + bias[o] )
// feat[b,2c,n] = x[b,c,n]; feat[b,2c+1,n] = max_k( x[b,c,e0[b,n,k]] - x[b,c,e1[b,n,k]] )
//
// v2: fused gather+GEMM. Gather writes feat tile (64 nodes x 384 ch bf16)
// directly into the swizzled LDS granule layout the GEMM reads -> featT
// intermediate (31 MB write + 31 MB read + grid sync) eliminated.
// b = blockIdx&3 keeps each batch's xT (3.84 MB) pinned to 2 XCDs' L2.

#define NB   4
#define NC   192
#define NN   10000
#define NK   16
#define NOUT 384
#define K2C  384            // 2*C

typedef short bf16x8 __attribute__((ext_vector_type(8)));  // 8 bf16 = 4 VGPRs
typedef float f32x4  __attribute__((ext_vector_type(4)));

__device__ inline unsigned short f2bf(float f) {
    unsigned int u = __builtin_bit_cast(unsigned int, f);
    u += ((u >> 16) & 1u) + 0x7FFFu;
    return (unsigned short)(u >> 16);
}
__device__ inline float bflo(unsigned int u) {           // low bf16 of dword -> f32
    return __builtin_bit_cast(float, u << 16);
}
__device__ inline float bfhi(unsigned int u) {           // high bf16 of dword -> f32
    return __builtin_bit_cast(float, u & 0xFFFF0000u);
}

// ---------------- K1: prep = transpose x -> xT bf16  +  W f32 -> bf16 ----------------
// blocks [0,628): transpose x[b][c][n] f32 -> xT[b][n][c] bf16
// blocks [628,772): wconv, float4-vectorized (36864 float4 = 144 blocks * 256)
__global__ __launch_bounds__(256) void k_prep(const float* __restrict__ x,
                                              unsigned short* __restrict__ xT,
                                              const float* __restrict__ w,
                                              unsigned short* __restrict__ wbf) {
    __shared__ unsigned short tile[NC * 65];   // 192 x 64 (+1 pad)
    int bid = blockIdx.x;
    if (bid >= 628) {                          // ---- wconv part ----
        int i = (bid - 628) * 256 + threadIdx.x;       // [0, 36864)
        float4 v = ((const float4*)w)[i];
        uint2 o;
        o.x = (unsigned int)f2bf(v.x) | ((unsigned int)f2bf(v.y) << 16);
        o.y = (unsigned int)f2bf(v.z) | ((unsigned int)f2bf(v.w) << 16);
        ((uint2*)wbf)[i] = o;
        return;
    }
    int b  = bid & 3;
    int nb = (bid >> 2) * 64;
    int t  = threadIdx.x;
    const float* xb = x + (size_t)b * NC * NN;
    for (int i = 0; i < 48; ++i) {             // 192*64/256 = 48
        int idx = i * 256 + t;
        int c  = idx >> 6;
        int nl = idx & 63;
        int n  = nb + nl;
        float v = (n < NN) ? xb[(size_t)c * NN + n] : 0.f;   // coalesced along n
        tile[c * 65 + nl] = f2bf(v);
    }
    __syncthreads();
    unsigned short* xTb = xT + (size_t)b * NN * NC;
    for (int i = 0; i < 48; ++i) {
        int idx = i * 256 + t;
        int nl  = idx / NC;
        int c   = idx - nl * NC;
        int n   = nb + nl;
        if (n < NN) xTb[(size_t)n * NC + c] = tile[c * 65 + nl];  // coalesced along c
    }
}

// ---------------- K2: fused gather + max-relative + GEMM ----------------
// Block: 64 nodes, 256 threads. Phase 1 (gather): half-wave per node, dword
// (2-ch) loads from xT; packed (x|m) dwords written straight into swizzled
// LDS granules: slot(n,j) = n*48 + (j+3n)%48, lane's uint2 = half granule.
// Phase 2 (GEMM): 4 waves, each 96 outs x 64 nodes (6x4 frags 16x16x32 bf16);
// W (A-operand) direct from global (L2-resident, 295 KB); relu+bias store.
__global__ __launch_bounds__(256, 3) void k_fused(const unsigned short* __restrict__ xT,
                                                  const int* __restrict__ eidx,
                                                  const unsigned short* __restrict__ wbf,
                                                  const float* __restrict__ bias,
                                                  float* __restrict__ out) {
    __shared__ unsigned short lds[64 * 48 * 8];   // 3072 granules of 16B = 48 KB
    int bid  = blockIdx.x;
    int b    = bid & 3;                           // XCD-pins xT[b] to 2 XCDs
    int nt   = bid >> 2;                          // 0..156
    int wv   = threadIdx.x >> 6;
    int lane = threadIdx.x & 63;
    int lam  = lane & 31;                         // lane within half-wave
    int hb   = lane & 32;                         // half-wave base for shfl
    int r    = lane & 15;
    int q    = lane >> 4;

    // ---- phase 1: gather + max-relative into LDS ----
    const unsigned int* xr = (const unsigned int*)(xT + (size_t)b * NN * NC); // rows of 96 dwords
    int part = lam >> 4;                          // 0 -> e0 (x_j), 1 -> e1 (x_i)
    const int* ep = eidx + (size_t)part * NB * NN * NK + (size_t)b * NN * NK;
    int nlb = wv * 16 + (hb ? 8 : 0);             // local node base
    int gnb = nt * 64 + nlb;                      // global node base

    int v[8];
#pragma unroll
    for (int it = 0; it < 8; ++it) {
        int n = gnb + it;
        v[it] = (n < NN) ? ep[(size_t)n * NK + (lam & 15)] : 0;
    }

    uint2* l2 = (uint2*)lds;                      // 2 uint2 per granule
    for (int it = 0; it < 8; ++it) {
        int n = gnb + it;
        if (n >= NN) break;                       // uniform within half-wave
        int nl = nlb + it;
        const unsigned int* crow = xr + (size_t)n * 96;
        unsigned int c0 = crow[lam], c1 = crow[32 + lam], c2 = crow[64 + lam];
        float m0l = -INFINITY, m0h = -INFINITY;
        float m1l = -INFINITY, m1h = -INFINITY;
        float m2l = -INFINITY, m2h = -INFINITY;
#pragma unroll 4
        for (int k = 0; k < 16; ++k) {
            int j = __shfl(v[it], hb + k, 64);
            int i = __shfl(v[it], hb + 16 + k, 64);
            const unsigned int* rj = xr + (size_t)j * 96;
            const unsigned int* ri = xr + (size_t)i * 96;
            unsigned int j0 = rj[lam], j1 = rj[32 + lam], j2 = rj[64 + lam];
            unsigned int i0 = ri[lam], i1 = ri[32 + lam], i2 = ri[64 + lam];
            m0l = fmaxf(m0l, bflo(j0) - bflo(i0));  m0h = fmaxf(m0h, bfhi(j0) - bfhi(i0));
            m1l = fmaxf(m1l, bflo(j1) - bflo(i1));  m1h = fmaxf(m1h, bfhi(j1) - bfhi(i1));
            m2l = fmaxf(m2l, bflo(j2) - bflo(i2));  m2h = fmaxf(m2h, bfhi(j2) - bfhi(i2));
        }
        // feat dwords: lane's c-dword d -> feat channels [4*lane_d, 4*lane_d+4)
        uint2 o0, o1, o2;
        o0.x = (c0 & 0xFFFFu)  | ((unsigned int)f2bf(m0l) << 16);
        o0.y = (c0 >> 16)      | ((unsigned int)f2bf(m0h) << 16);
        o1.x = (c1 & 0xFFFFu)  | ((unsigned int)f2bf(m1l) << 16);
        o1.y = (c1 >> 16)      | ((unsigned int)f2bf(m1h) << 16);
        o2.x = (c2 & 0xFFFFu)  | ((unsigned int)f2bf(m2l) << 16);
        o2.y = (c2 >> 16)      | ((unsigned int)f2bf(m2h) << 16);
        // granule j for o0 = lam>>1; o1 = 16+lam>>1; o2 = 32+lam>>1; half = lam&1
        unsigned int g  = (unsigned int)(lam >> 1);
        unsigned int nw = (unsigned int)nl;
        unsigned int s0 = nw * 48u + (g        + 3u * nw) % 48u;
        unsigned int s1 = nw * 48u + (g + 16u  + 3u * nw) % 48u;
        unsigned int s2 = nw * 48u + (g + 32u  + 3u * nw) % 48u;
        unsigned int half = (unsigned int)(lam & 1);
        l2[2u * s0 + half] = o0;
        l2[2u * s1 + half] = o1;
        l2[2u * s2 + half] = o2;
    }

    __syncthreads();

    // ---- phase 2: GEMM ----
    const unsigned short* aptr = wbf + (size_t)(wv * 96 + r) * K2C + q * 8;

    unsigned int nbase[4], u0[4];
#pragma unroll
    for (int ni = 0; ni < 4; ++ni) {
        unsigned int n = ni * 16 + r;
        nbase[ni] = n * 48u;
        u0[ni] = ((unsigned int)q + 3u * n) % 48u;
    }

    f32x4 acc[6][4];
#pragma unroll
    for (int mi = 0; mi < 6; ++mi)
#pragma unroll
        for (int ni = 0; ni < 4; ++ni)
            acc[mi][ni] = (f32x4){0.f, 0.f, 0.f, 0.f};

#pragma unroll 2
    for (int t = 0; t < 12; ++t) {
        bf16x8 a[6], bb[4];
#pragma unroll
        for (int mi = 0; mi < 6; ++mi)
            a[mi] = *(const bf16x8*)(aptr + (size_t)mi * 16 * K2C + t * 32);
#pragma unroll
        for (int ni = 0; ni < 4; ++ni) {
            unsigned int u = u0[ni] + 4u * t;
            if (u >= 48u) u -= 48u;
            bb[ni] = *(const bf16x8*)(lds + (size_t)(nbase[ni] + u) * 8);
        }
#pragma unroll
        for (int mi = 0; mi < 6; ++mi)
#pragma unroll
            for (int ni = 0; ni < 4; ++ni)
                acc[mi][ni] = __builtin_amdgcn_mfma_f32_16x16x32_bf16(a[mi], bb[ni], acc[mi][ni], 0, 0, 0);
    }

    float* ob = out + (size_t)b * NOUT * NN;
#pragma unroll
    for (int mi = 0; mi < 6; ++mi) {
        int obase = wv * 96 + mi * 16 + q * 4;
#pragma unroll
        for (int ni = 0; ni < 4; ++ni) {
            int n = nt * 64 + ni * 16 + r;
            if (n < NN) {
#pragma unroll
                for (int rr = 0; rr < 4; ++rr) {
                    int o = obase + rr;
                    float val = acc[mi][ni][rr] + bias[o];
                    ob[(size_t)o * NN + n] = fmaxf(val, 0.f);
                }
            }
        }
    }
}

extern "C" void kernel_launch(void* const* d_in, const int* in_sizes, int n_in,
                              void* d_out, int out_size, void* d_ws, size_t ws_size,
                              hipStream_t stream) {
    const float* x    = (const float*)d_in[0];   // [4,192,10000,1]
    const int*   eidx = (const int*)d_in[1];     // [2,4,10000,16]
    const float* w    = (const float*)d_in[2];   // [384,384]
    const float* bias = (const float*)d_in[3];   // [384]
    float* out = (float*)d_out;                  // [4,384,10000,1,1]

    // workspace: xT [4][10000][192] bf16 (15.36 MB) | wbf [384][384] bf16 (0.29 MB)
    unsigned short* xT  = (unsigned short*)d_ws;
    unsigned short* wbf = xT + (size_t)NB * NN * NC;

    hipLaunchKernelGGL(k_prep,  dim3(628 + 144), dim3(256), 0, stream, x, xT, w, wbf);
    hipLaunchKernelGGL(k_fused, dim3(4 * 157),   dim3(256), 0, stream, xT, eidx, wbf, bias, out);
}